// Round 1
// baseline (9743.255 us; speedup 1.0000x reference)
//
#include <hip/hip_runtime.h>
#include <math.h>

// Problem sizes (fixed by reference)
#define TT 2048
#define BB 64
#define IIN 128
#define HHID 512
#define OOUT 64
#define OUT_OFF (BB * HHID)   // h_final [B,H] then outs [B,T,O]

// Decomposition: 16 groups x 16 WGs; each group owns 4 batches; each WG owns
// 32 h-rows (+4 Who rows folded in as rows 32..35, rows 36..39 zero pad).
#define NGRP 16
#define WPG 16
#define BPG 4
#define JW 32
#define ROWS 40
#define NTHR 320   // 5 waves: thread = (j2 = tid>>4 in [0,20), s = tid&15)

// LDS layout (float offsets)
#define LDS_W 0                               // [40][512]
#define LDS_WIH (LDS_W + ROWS * 512)          // [32][128]
#define LDS_TH (LDS_WIH + 32 * 128)           // [4][516]
#define TH_STRIDE 516
#define LDS_X (LDS_TH + 4 * TH_STRIDE)        // [4][132]
#define X_STRIDE 132
#define LDS_NRE (LDS_X + 4 * X_STRIDE)        // [4][32]
#define LDS_PART (LDS_NRE + 128)              // [16][163] (b*40+row < 163)
#define PART_STRIDE 163
#define LDS_BHH (LDS_PART + 16 * PART_STRIDE)
#define LDS_BHO (LDS_BHH + 32)
#define LDS_TOTAL (LDS_BHO + 4)               // 29940 floats = 119760 B

// Bank-conflict swizzles (write and read use the same involution)
__device__ __forceinline__ int swzW(int j2key, int k) {
  // rows stride 512 words: without this, the 16 s-lanes (k step 32) all wrap
  // to one bank quad. XOR k bits[2:4] with (s ^ j2).
  return k ^ (4 * (((k >> 5) ^ j2key) & 7));
}
__device__ __forceinline__ int swzT(int k) {
  return k ^ (4 * ((k >> 5) & 7));
}
__device__ __forceinline__ int swzI(int j2key, int i) {
  return i ^ (4 * (j2key & 1));
}

extern "C" __global__ void __launch_bounds__(NTHR, 1)
rnn_kernel(const float* __restrict__ inputs,
           const float* __restrict__ hidden,
           const float* __restrict__ in_noise,
           const float* __restrict__ re_noise,
           const float* __restrict__ Wih,
           const float* __restrict__ Whh,
           const float* __restrict__ bhh,
           const float* __restrict__ Who,
           const float* __restrict__ bho,
           float* __restrict__ out,
           unsigned int* __restrict__ cnt,   // [16] counters, stride 64 dwords
           float* __restrict__ th_buf)       // [2][16][4][512] f32
{
  extern __shared__ float smem[];
  const int tid = threadIdx.x;
  const int g = blockIdx.x & 15;   // group: members share blockIdx%16 -> same XCD slot under round-robin (perf only)
  const int w = blockIdx.x >> 4;   // member 0..15
  const int j0 = w * JW;

  // ---------------- stage weights into LDS (once) ----------------
  for (int c = tid; c < 32 * 128; c += NTHR) {       // Whh slice rows 0..31
    int j = c >> 7, k4 = (c & 127) << 2;
    float4 v = *(const float4*)&Whh[(long)(j0 + j) * HHID + k4];
    *(float4*)&smem[LDS_W + j * 512 + swzW(j >> 1, k4)] = v;
  }
  for (int c = tid; c < 4 * 128; c += NTHR) {        // Who rows 32..35
    int oc = c >> 7, k4 = (c & 127) << 2;
    int r = 32 + oc;
    float4 v = *(const float4*)&Who[(long)(4 * w + oc) * HHID + k4];
    *(float4*)&smem[LDS_W + r * 512 + swzW(r >> 1, k4)] = v;
  }
  for (int c = tid; c < 4 * 128; c += NTHR) {        // zero pad rows 36..39
    int pr = c >> 7, k4 = (c & 127) << 2;
    int r = 36 + pr;
    float4 z = make_float4(0.f, 0.f, 0.f, 0.f);
    *(float4*)&smem[LDS_W + r * 512 + swzW(r >> 1, k4)] = z;
  }
  for (int c = tid; c < 32 * 32; c += NTHR) {        // Wih slice
    int j = c >> 5, i4 = (c & 31) << 2;
    float4 v = *(const float4*)&Wih[(long)(j0 + j) * IIN + i4];
    *(float4*)&smem[LDS_WIH + j * 128 + swzI(j >> 1, i4)] = v;
  }
  if (tid < 32) smem[LDS_BHH + tid] = bhh[j0 + tid];
  if (tid < 4)  smem[LDS_BHO + tid] = bho[4 * w + tid];

  // ---------------- init h, publish th(-1) into buf0 ----------------
  float hreg = 0.f;
  if (tid < 160) {
    int b = tid & 3, row = tid >> 2;   // owner mapping
    if (row < JW) {
      hreg = hidden[(long)(4 * g + b) * HHID + j0 + row];
      float th0 = tanhf(hreg);
      __hip_atomic_store(&th_buf[((0 * NGRP + g) * BPG + b) * HHID + j0 + row],
                         th0, __ATOMIC_RELAXED, __HIP_MEMORY_SCOPE_AGENT);
    }
  }
  __syncthreads();   // implies vmcnt(0) per thread before barrier
  if (tid == 0)
    __hip_atomic_fetch_add(&cnt[g * 64], 1u, __ATOMIC_RELAXED, __HIP_MEMORY_SCOPE_AGENT);

  const int j2 = tid >> 4;       // 0..19
  const int s  = tid & 15;       // k-chunk
  const int r0 = j2 << 1;

  for (int t = 0; t <= TT; ++t) {
    // ---- issue HBM stream loads for step t (hidden under the spin) ----
    float4 xin = make_float4(0, 0, 0, 0), xno = make_float4(0, 0, 0, 0);
    float nre_v = 0.f;
    if (t < TT) {
      if (tid < 128) {
        int b = tid >> 5, i4 = (tid & 31) << 2;
        long off = ((long)(4 * g + b) * TT + t) * IIN + i4;
        xin = *(const float4*)&inputs[off];
        xno = *(const float4*)&in_noise[off];
      } else if (tid < 256) {
        int q = tid - 128, b = q >> 5, row = q & 31;
        nre_v = re_noise[((long)(4 * g + b) * TT + t) * HHID + j0 + row];
      }
    }
    // ---- wait until all 16 WGs published th(t-1) ----
    if (tid == 0) {
      unsigned tgt = 16u * (unsigned)(t + 1);
      while (__hip_atomic_load(&cnt[g * 64], __ATOMIC_RELAXED,
                               __HIP_MEMORY_SCOPE_AGENT) < tgt) { }
    }
    __syncthreads();
    // ---- consume th(t-1) from buf[t&1] into LDS (swizzled) ----
    {
      const float* src = &th_buf[((t & 1) * NGRP + g) * BPG * HHID];
      float vv[6];
      #pragma unroll
      for (int it = 0; it < 6; ++it)
        vv[it] = __hip_atomic_load(&src[tid + it * NTHR], __ATOMIC_RELAXED,
                                   __HIP_MEMORY_SCOPE_AGENT);
      float vt = 0.f;
      if (tid < 128)
        vt = __hip_atomic_load(&src[1920 + tid], __ATOMIC_RELAXED,
                               __HIP_MEMORY_SCOPE_AGENT);
      #pragma unroll
      for (int it = 0; it < 6; ++it) {
        int e = tid + it * NTHR, b = e >> 9, k = e & 511;
        smem[LDS_TH + b * TH_STRIDE + swzT(k)] = vv[it];
      }
      if (tid < 128) {
        int e = 1920 + tid, b = e >> 9, k = e & 511;
        smem[LDS_TH + b * TH_STRIDE + swzT(k)] = vt;
      }
    }
    if (t < TT) {
      if (tid < 128) {
        int b = tid >> 5, i4 = (tid & 31) << 2;
        float4 xv;
        xv.x = xin.x * (1.f + 0.01f * xno.x);
        xv.y = xin.y * (1.f + 0.01f * xno.y);
        xv.z = xin.z * (1.f + 0.01f * xno.z);
        xv.w = xin.w * (1.f + 0.01f * xno.w);
        *(float4*)&smem[LDS_X + b * X_STRIDE + i4] = xv;
      } else if (tid < 256) {
        smem[LDS_NRE + (tid - 128)] = nre_v;   // [b*32+row]
      }
    }
    __syncthreads();

    // ---- main compute: rows r0,r0+1 vs all 4 batches ----
    float a00 = 0, a01 = 0, a10 = 0, a11 = 0, a20 = 0, a21 = 0, a30 = 0, a31 = 0;
    #pragma unroll
    for (int c8 = 0; c8 < 8; ++c8) {
      int k = (s << 5) + (c8 << 2);
      int kw = swzW(j2, k);
      int kt = swzT(k);
      float4 w0 = *(const float4*)&smem[LDS_W + r0 * 512 + kw];
      float4 w1 = *(const float4*)&smem[LDS_W + (r0 + 1) * 512 + kw];
      float4 t0 = *(const float4*)&smem[LDS_TH + 0 * TH_STRIDE + kt];
      float4 t1 = *(const float4*)&smem[LDS_TH + 1 * TH_STRIDE + kt];
      float4 t2 = *(const float4*)&smem[LDS_TH + 2 * TH_STRIDE + kt];
      float4 t3 = *(const float4*)&smem[LDS_TH + 3 * TH_STRIDE + kt];
      a00 += w0.x * t0.x + w0.y * t0.y + w0.z * t0.z + w0.w * t0.w;
      a01 += w1.x * t0.x + w1.y * t0.y + w1.z * t0.z + w1.w * t0.w;
      a10 += w0.x * t1.x + w0.y * t1.y + w0.z * t1.z + w0.w * t1.w;
      a11 += w1.x * t1.x + w1.y * t1.y + w1.z * t1.z + w1.w * t1.w;
      a20 += w0.x * t2.x + w0.y * t2.y + w0.z * t2.z + w0.w * t2.w;
      a21 += w1.x * t2.x + w1.y * t2.y + w1.z * t2.z + w1.w * t2.w;
      a30 += w0.x * t3.x + w0.y * t3.y + w0.z * t3.z + w0.w * t3.w;
      a31 += w1.x * t3.x + w1.y * t3.y + w1.z * t3.z + w1.w * t3.w;
    }
    if (j2 < 16) {   // Wih part only for h-rows (waves 0..3, uniform)
      #pragma unroll
      for (int c2 = 0; c2 < 2; ++c2) {
        int i = (s << 3) + (c2 << 2);
        int iw = swzI(j2, i);
        float4 w0 = *(const float4*)&smem[LDS_WIH + r0 * 128 + iw];
        float4 w1 = *(const float4*)&smem[LDS_WIH + (r0 + 1) * 128 + iw];
        float4 x0 = *(const float4*)&smem[LDS_X + 0 * X_STRIDE + i];
        float4 x1 = *(const float4*)&smem[LDS_X + 1 * X_STRIDE + i];
        float4 x2 = *(const float4*)&smem[LDS_X + 2 * X_STRIDE + i];
        float4 x3 = *(const float4*)&smem[LDS_X + 3 * X_STRIDE + i];
        a00 += w0.x * x0.x + w0.y * x0.y + w0.z * x0.z + w0.w * x0.w;
        a01 += w1.x * x0.x + w1.y * x0.y + w1.z * x0.z + w1.w * x0.w;
        a10 += w0.x * x1.x + w0.y * x1.y + w0.z * x1.z + w0.w * x1.w;
        a11 += w1.x * x1.x + w1.y * x1.y + w1.z * x1.z + w1.w * x1.w;
        a20 += w0.x * x2.x + w0.y * x2.y + w0.z * x2.z + w0.w * x2.w;
        a21 += w1.x * x2.x + w1.y * x2.y + w1.z * x2.z + w1.w * x2.w;
        a30 += w0.x * x3.x + w0.y * x3.y + w0.z * x3.z + w0.w * x3.w;
        a31 += w1.x * x3.x + w1.y * x3.y + w1.z * x3.z + w1.w * x3.w;
      }
    }
    // partials [s][b*40+row]
    smem[LDS_PART + s * PART_STRIDE + 0 * 40 + r0]     = a00;
    smem[LDS_PART + s * PART_STRIDE + 0 * 40 + r0 + 1] = a01;
    smem[LDS_PART + s * PART_STRIDE + 1 * 40 + r0]     = a10;
    smem[LDS_PART + s * PART_STRIDE + 1 * 40 + r0 + 1] = a11;
    smem[LDS_PART + s * PART_STRIDE + 2 * 40 + r0]     = a20;
    smem[LDS_PART + s * PART_STRIDE + 2 * 40 + r0 + 1] = a21;
    smem[LDS_PART + s * PART_STRIDE + 3 * 40 + r0]     = a30;
    smem[LDS_PART + s * PART_STRIDE + 3 * 40 + r0 + 1] = a31;
    __syncthreads();

    // ---- reduce + h update + publish th(t) / store out(t-1) ----
    if (tid < 160) {
      int b = tid & 3, row = tid >> 2;
      float sum = 0.f;
      #pragma unroll
      for (int ss = 0; ss < 16; ++ss)
        sum += smem[LDS_PART + ss * PART_STRIDE + b * 40 + row];
      if (row < JW) {
        if (t < TT) {
          float dh = -hreg + sum + smem[LDS_BHH + row]
                     + 0.01f * smem[LDS_NRE + b * 32 + row];
          hreg += 0.1f * dh;   // ALPHA = DT/TAU = 0.1
          float thv = tanhf(hreg);
          __hip_atomic_store(
              &th_buf[((((t + 1) & 1) * NGRP + g) * BPG + b) * HHID + j0 + row],
              thv, __ATOMIC_RELAXED, __HIP_MEMORY_SCOPE_AGENT);
        }
      } else if (row < 36) {
        if (t > 0) {
          int oc = row - 32;
          long oof = (long)OUT_OFF + ((long)(4 * g + b) * TT + (t - 1)) * OOUT
                     + 4 * w + oc;
          out[oof] = sum + smem[LDS_BHO + oc];
        }
      }
    }
    __syncthreads();   // drains publish stores (vmcnt(0)) before arrival
    if (tid == 0 && t < TT)
      __hip_atomic_fetch_add(&cnt[g * 64], 1u, __ATOMIC_RELAXED,
                             __HIP_MEMORY_SCOPE_AGENT);
  }

  // ---- final hidden state ----
  if (tid < 160) {
    int b = tid & 3, row = tid >> 2;
    if (row < JW)
      out[(long)(4 * g + b) * HHID + j0 + row] = hreg;
  }
}

extern "C" void kernel_launch(void* const* d_in, const int* in_sizes, int n_in,
                              void* d_out, int out_size, void* d_ws, size_t ws_size,
                              hipStream_t stream) {
  const float* inputs  = (const float*)d_in[0];
  const float* hidden  = (const float*)d_in[1];
  const float* innoise = (const float*)d_in[2];
  const float* renoise = (const float*)d_in[3];
  const float* Wih     = (const float*)d_in[4];
  const float* Whh     = (const float*)d_in[5];
  const float* bhh     = (const float*)d_in[6];
  const float* Who     = (const float*)d_in[7];
  const float* bho     = (const float*)d_in[8];
  float* out = (float*)d_out;

  unsigned int* cnt = (unsigned int*)d_ws;                 // 16 counters, 256B apart
  float* th_buf = (float*)((char*)d_ws + 4096);            // 2*16*4*512 f32 = 256KB

  hipMemsetAsync(d_ws, 0, 4096, stream);                   // reset epoch counters

  int lds_bytes = LDS_TOTAL * 4;
  hipFuncSetAttribute(reinterpret_cast<const void*>(rnn_kernel),
                      hipFuncAttributeMaxDynamicSharedMemorySize, lds_bytes);
  hipLaunchKernelGGL(rnn_kernel, dim3(256), dim3(NTHR), lds_bytes, stream,
                     inputs, hidden, innoise, renoise, Wih, Whh, bhh, Who, bho,
                     out, cnt, th_buf);
}